// Round 16
// baseline (35.893 us; speedup 1.0000x reference)
//
#include <hip/hip_runtime.h>
#include <hip/hip_bf16.h>

// SparseGCM: 2-layer causal-window GCN on MI355X — split-bf16, fragment-
// contiguous layout, 3-kernel chain, BOTH gemms with LDS-shared A:
//   prep_fused -> gemm1_fused (LDS-A + halo winsum epilogue) -> gemm2_lds.
//
// Edges are j->i for j in [i-16,i) per batch, weights normalize to 1.0 ->
// "gather+segment_sum" == 16-wide sliding-window sum. Only outputs i in
// [512,640) matter: layer1 computes i in [496,640).
//
// Precision (R2/R4): single-bf16 fails (correlated L1 errors x16-amplified by
// the L2 window sum). Split v = hi+lo bf16; compute Ahi*Whi + Ahi*Wlo +
// Alo*Whi (3 MFMAs) ~= fp32. Validated R5-R15 (absmax 0.0039).
//
// Perf history: R5 61.2; R6 99.5; R7 55.8; R8 49.7; R9 ABORT (compiler reg
// loads inside asm-vmcnt region); R10 47.8; R11 45.5; R12 41.2; R13 41.7
// (SBAR-only NEUTRAL); R14 37.4 (gemm1 LDS-A); R15 35.8 (gemm2 LDS-A).
// R16: deepen both gemm pipelines depth-2 -> depth-3 (4 LDS stage buffers +
// 4 W register slots) to cover the ~500-900cy L3/remote-L2 latency of the
// freshly-written A-streams. Cohort FIFO waits: gemm1 vmcnt(10)/(8) by wave
// class, gemm2 vmcnt(8); tails 5/4 -> 0. Same overwrite-safety invariant.

namespace {

constexpr int BQ    = 64;
constexpr int FEATC = 256;
constexpr int M1 = 144;   // layer-1 rows/batch: i in [496,640)
constexpr int M2 = 128;   // layer-2 rows/batch: i in [512,640)

using ushort = unsigned short;
using short8 = __attribute__((ext_vector_type(8))) short;   // 8 bf16
using f32x4  = __attribute__((ext_vector_type(4))) float;

__device__ __forceinline__ ushort f2bf(float f) {  // RNE
  union { float f; unsigned u; } v{f};
  unsigned r = v.u + 0x7FFFu + ((v.u >> 16) & 1u);
  return (ushort)(r >> 16);
}
__device__ __forceinline__ float bf2f(ushort h) {
  union { unsigned u; float f; } v{(unsigned)h << 16};
  return v.f;
}
__device__ __forceinline__ void split2(float v, ushort& hi, ushort& lo) {
  hi = f2bf(v);
  lo = f2bf(v - bf2f(hi));
}
// tanh(x) = 1 - 2/(1 + exp2(2*log2e*x)); exp2/rcp handle the limits.
__device__ __forceinline__ float tanh_fast(float x) {
  const float e = __builtin_amdgcn_exp2f(x * 2.8853900817779268f);
  return 1.0f - 2.0f * __builtin_amdgcn_rcpf(1.0f + e);
}
__device__ __forceinline__ void gl_lds16(const ushort* g, ushort* l) {
  __builtin_amdgcn_global_load_lds(
      (const __attribute__((address_space(1))) void*)g,
      (__attribute__((address_space(3))) void*)l, 16, 0, 0);
}

// Fragment-contiguous layout. Row r, packed k in [0,512) ([self|win] for A,
// [Wself|Wnbr] for W), s = hi(0)/lo(1) (for W: W1/W2). A wave's MFMA fragment
// = contiguous 1KB block at ((rg*16 + kb)*2 + s)*512, lane-linear inside.
__device__ __forceinline__ size_t frag_idx(int row, int k, int s) {
  return ((size_t)(((row >> 4) * 16 + (k >> 5)) * 2 + s)) * 512
       + ((k >> 3) & 3) * 128 + (row & 15) * 8 + (k & 7);
}
// Same, local to one 16-row group (16384-elem block).
__device__ __forceinline__ int lofs(int row_l, int k, int s) {
  return ((k >> 5) * 2 + s) * 512 + ((k >> 3) & 3) * 128 + row_l * 8 + (k & 7);
}

// ---------------------------------------------------------------------------
// prep_fused: blocks [0,576) = prep1 (A1F via LDS burst, XCD-permuted);
//             blocks [576,640) = weight transpose+split.
// ---------------------------------------------------------------------------
__global__ __launch_bounds__(256) void prep_fused(
    const float* __restrict__ x, const float* __restrict__ nodes,
    const float* __restrict__ W1s, const float* __restrict__ W1n,
    const float* __restrict__ W2s, const float* __restrict__ W2n,
    ushort* __restrict__ A1F, ushort* __restrict__ WF1,
    ushort* __restrict__ WF2) {
  __shared__ ushort lds_o[16384];   // one 16-row frag group (32 KB)
  __shared__ float tile[64][65];
  const int blk = blockIdx.x;
  if (blk < 576) {
    const int G = 4 * (blk % 144) + (blk / 144);   // XCD spread permutation
    const int b = G / 9, c = G % 9, f = threadIdx.x;
    const int t0 = c * 16, i0 = 496 + t0;
    const float* nb = nodes + ((size_t)b * 640) * FEATC + f;
    const float* xb = x     + ((size_t)b * 128) * FEATC + f;

    float v[32];
    #pragma unroll
    for (int d = 0; d < 32; ++d) {
      const int i = i0 - 16 + d;
      v[d] = (i < 512) ? nb[(size_t)i * FEATC] : xb[(size_t)(i - 512) * FEATC];
    }
    float win = 0.f;
    #pragma unroll
    for (int d = 0; d < 16; ++d) win += v[d];

    #pragma unroll
    for (int tt = 0; tt < 16; ++tt) {
      ushort hi, lo;
      split2(v[16 + tt], hi, lo);
      lds_o[lofs(tt, f, 0)] = hi;
      lds_o[lofs(tt, f, 1)] = lo;
      split2(win, hi, lo);
      lds_o[lofs(tt, 256 + f, 0)] = hi;
      lds_o[lofs(tt, 256 + f, 1)] = lo;
      win += v[16 + tt] - v[tt];
    }
    __syncthreads();
    ushort* dst = A1F + (size_t)G * 16384;
    #pragma unroll
    for (int it = 0; it < 8; ++it) {
      const int idx = it * 256 + threadIdx.x;
      *(short8*)(dst + idx * 8) = *(const short8*)(lds_o + idx * 8);
    }
  } else {
    const int w = blk - 576;
    const int z = w >> 4, rem = w & 15;
    const int k0 = (rem >> 2) * 64, n0 = (rem & 3) * 64;
    const float* src = (z == 0) ? W1s : (z == 1) ? W1n : (z == 2) ? W2s : W2n;
    ushort* dst = (z < 2) ? WF1 : WF2;
    const int koff = (z & 1) * 256;
    const int c = threadIdx.x & 63, r4 = threadIdx.x >> 6;
    #pragma unroll
    for (int p = 0; p < 16; ++p) {
      const int k = r4 + p * 4;
      tile[k][c] = src[(size_t)(k0 + k) * FEATC + n0 + c];
    }
    __syncthreads();
    #pragma unroll
    for (int p = 0; p < 16; ++p) {
      const int n = r4 + p * 4;
      ushort hi, lo;
      split2(tile[c][n], hi, lo);
      dst[frag_idx(n0 + n, koff + k0 + c, 0)] = hi;   // W1 (hi) slot
      dst[frag_idx(n0 + n, koff + k0 + c, 1)] = lo;   // W2 (lo) slot
    }
  }
}

// ---------------------------------------------------------------------------
// Shared asm helpers. Rules: only asm vmem / gl_lds builtin inside pipelined
// regions; counted vmcnt via asm; raw barrier via builtin (no drain).
// ---------------------------------------------------------------------------
#define GLOAD(dst, ptr)                                                      \
  asm volatile("global_load_dwordx4 %0, %1, off"                             \
               : "=v"(dst) : "v"(ptr) : "memory")

#define WAITV(n) do {                                                        \
  asm volatile("s_waitcnt vmcnt(" #n ")" ::: "memory");                      \
  __builtin_amdgcn_sched_barrier(0);                                         \
} while (0)

#define MF(a, b, c) c = __builtin_amdgcn_mfma_f32_16x16x32_bf16(a, b, c, 0, 0, 0)

// ---------------------------------------------------------------------------
// gemm1_fused: 80-row h1 window (16-row halo), A staged in LDS once per
// block, depth-3 (4 buffers); W per-wave asm 4-slot rotation. Cohort/step:
// waves 0,1 = 3 stage + 2 W = 5 ops; waves 2,3 = 2 + 2 = 4. Steady wait =
// 2 cohorts -> vmcnt(10)/(8); tails 5/4 -> 0. Winsum epilogue emits A2F.
// ---------------------------------------------------------------------------
#define STAGEA(jn, kb) do {                                                  \
  gl_lds16(srcu0 + (kb) * 1024, sbase + (jn) * 5120 + u0 * 512);             \
  gl_lds16(srcu1 + (kb) * 1024, sbase + (jn) * 5120 + u1 * 512);             \
  if (g3) gl_lds16(srcu2 + (kb) * 1024, sbase + (jn) * 5120 + u2 * 512);     \
} while (0)

#define WAITW  do { if (g3) { WAITV(10); } else { WAITV(8); } } while (0)
#define WAITW1 do { if (g3) { WAITV(5); }  else { WAITV(4); } } while (0)

#define COMPJ2(j, WH, WL) do {                                               \
  const ushort* bp_ = sbase + (j) * 5120 + lane * 8;                         \
  const short8 a0h = *(const short8*)(bp_ + 0 * 512);                        \
  const short8 a0l = *(const short8*)(bp_ + 1 * 512);                        \
  const short8 a1h = *(const short8*)(bp_ + 2 * 512);                        \
  const short8 a1l = *(const short8*)(bp_ + 3 * 512);                        \
  const short8 a2h = *(const short8*)(bp_ + 4 * 512);                        \
  const short8 a2l = *(const short8*)(bp_ + 5 * 512);                        \
  const short8 a3h = *(const short8*)(bp_ + 6 * 512);                        \
  const short8 a3l = *(const short8*)(bp_ + 7 * 512);                        \
  const short8 a4h = *(const short8*)(bp_ + 8 * 512);                        \
  const short8 a4l = *(const short8*)(bp_ + 9 * 512);                        \
  __builtin_amdgcn_s_setprio(1);                                            \
  MF(a0h, WH, acc[0]); MF(a1h, WH, acc[1]); MF(a2h, WH, acc[2]);             \
  MF(a3h, WH, acc[3]); MF(a4h, WH, acc[4]);                                  \
  MF(a0h, WL, acc[0]); MF(a1h, WL, acc[1]); MF(a2h, WL, acc[2]);             \
  MF(a3h, WL, acc[3]); MF(a4h, WL, acc[4]);                                  \
  MF(a0l, WH, acc[0]); MF(a1l, WH, acc[1]); MF(a2l, WH, acc[2]);             \
  MF(a3l, WH, acc[3]); MF(a4l, WH, acc[4]);                                  \
  __builtin_amdgcn_s_setprio(0);                                            \
  __builtin_amdgcn_sched_barrier(0);                                        \
} while (0)

__global__ __launch_bounds__(256, 2) void gemm1_fused(
    const ushort* __restrict__ A, const ushort* __restrict__ W,
    const float* __restrict__ bias, ushort* __restrict__ A2F) {
  // LDS union: [0,40960) = 4 stage bufs (10KB each) during main loop;
  // epilogue reuses: hvt 80x68 f32 at 0 (21760B), outb at 21760 (32768B).
  __shared__ __align__(16) unsigned char ldsmem[54528];
  ushort* sbase = (ushort*)ldsmem;
  float (*hvt)[68] = (float(*)[68])ldsmem;
  ushort* outb = (ushort*)(ldsmem + 21760);

  const int tid = threadIdx.x;
  const int wave = tid >> 6, lane = tid & 63;
  const int lr = lane & 15, kg = lane >> 4;
  const int mx2 = blockIdx.x, ny = blockIdx.y;
  const int b = mx2 >> 1, half = mx2 & 1;
  const int rgA0 = 9 * b + 4 * half;          // first of 5 A row-groups
  const int n0 = ny * 64;
  const int ngw = ny * 4 + wave;              // W col-group for this wave

  // A staging unit assignment: unit u = g*2+s; waves 0,1 own {0..2},{3..5};
  // waves 2,3 own {6,7},{8,9}.
  const bool g3 = (wave < 2);
  const int uw = g3 ? wave * 3 : 6 + (wave - 2) * 2;
  const int u0 = uw, u1 = uw + 1, u2 = g3 ? uw + 2 : uw + 1;
  auto srcA = [&](int u) {
    return A + ((size_t)(rgA0 + (u >> 1)) * 32 + (u & 1)) * 512 + lane * 8;
  };
  const ushort* srcu0 = srcA(u0);
  const ushort* srcu1 = srcA(u1);
  const ushort* srcu2 = srcA(u2);

  const ushort* bW = W + (size_t)ngw * 16384 + lane * 8;

  f32x4 acc[5] = {};
  short8 w0h, w0l, w1h, w1l, w2h, w2l, w3h, w3l;

  // prologue: stage steps 0,1,2 (interleaved S,W -> FIFO cohorts)
  STAGEA(0, 0); GLOAD(w0h, bW);        GLOAD(w0l, bW + 512);
  STAGEA(1, 1); GLOAD(w1h, bW + 1024); GLOAD(w1l, bW + 1536);
  STAGEA(2, 2); GLOAD(w2h, bW + 2048); GLOAD(w2l, bW + 2560);

#define STEP(k, j, jn, WH, WL, NWH, NWL)                                     \
  WAITW; __builtin_amdgcn_s_barrier();                                       \
  COMPJ2(j, WH, WL);                                                         \
  STAGEA(jn, (k) + 3);                                                       \
  GLOAD(NWH, bW + ((k) + 3) * 1024); GLOAD(NWL, bW + ((k) + 3) * 1024 + 512)

  STEP(0,  0, 3, w0h, w0l, w3h, w3l);
  STEP(1,  1, 0, w1h, w1l, w0h, w0l);
  STEP(2,  2, 1, w2h, w2l, w1h, w1l);
  STEP(3,  3, 2, w3h, w3l, w2h, w2l);
  STEP(4,  0, 3, w0h, w0l, w3h, w3l);
  STEP(5,  1, 0, w1h, w1l, w0h, w0l);
  STEP(6,  2, 1, w2h, w2l, w1h, w1l);
  STEP(7,  3, 2, w3h, w3l, w2h, w2l);
  STEP(8,  0, 3, w0h, w0l, w3h, w3l);
  STEP(9,  1, 0, w1h, w1l, w0h, w0l);
  STEP(10, 2, 1, w2h, w2l, w1h, w1l);
  STEP(11, 3, 2, w3h, w3l, w2h, w2l);
  STEP(12, 0, 3, w0h, w0l, w3h, w3l);
  // tails: no more issues
  WAITW;    __builtin_amdgcn_s_barrier(); COMPJ2(1, w1h, w1l);
  WAITW1;   __builtin_amdgcn_s_barrier(); COMPJ2(2, w2h, w2l);
  WAITV(0); __builtin_amdgcn_s_barrier(); COMPJ2(3, w3h, w3l);
#undef STEP

  __syncthreads();   // LDS reuse boundary (stage bufs -> hvt/outb)

  // ---- epilogue 1: tanh -> LDS f32 tile [80 rows][64 cols] ----
  const float bv = bias[n0 + wave * 16 + lr];
  #pragma unroll
  for (int fr = 0; fr < 5; ++fr)
    #pragma unroll
    for (int r = 0; r < 4; ++r)
      hvt[fr * 16 + kg * 4 + r][wave * 16 + lr] = tanh_fast(acc[fr][r] + bv);
  __syncthreads();

  // ---- epilogue 2: per-column 16-window sums + split -> outb units ----
  {
    const int col = tid & 63, q = tid >> 6;
    float hv[32];
    #pragma unroll
    for (int d = 0; d < 32; ++d) hv[d] = hvt[q * 16 + d][col];
    float win = 0.f;
    #pragma unroll
    for (int d = 0; d < 16; ++d) win += hv[d];

    const int su = ((q * 4 + (col >> 5)) * 2) * 512
                 + ((col >> 3) & 3) * 128 + (col & 7);
    const int wu = ((q * 4 + 2 + (col >> 5)) * 2) * 512
                 + ((col >> 3) & 3) * 128 + (col & 7);
    #pragma unroll
    for (int tt = 0; tt < 16; ++tt) {
      ushort hi, lo;
      split2(hv[16 + tt], hi, lo);
      outb[su + tt * 8]       = hi;
      outb[su + tt * 8 + 512] = lo;
      split2(win, hi, lo);
      outb[wu + tt * 8]       = hi;
      outb[wu + tt * 8 + 512] = lo;
      win += hv[16 + tt] - hv[tt];
    }
  }
  __syncthreads();

  // ---- epilogue 3: burst copy 32 units of 1KB to A2F ----
  const int rg20 = 4 * mx2;
  #pragma unroll
  for (int it = 0; it < 8; ++it) {
    const int lin = it * 2048 + tid * 8;
    const int u = lin >> 9, w = lin & 511;
    const int uq = u >> 3, ukbl = (u >> 1) & 3, us = u & 1;
    const int KB = (ukbl < 2) ? (2 * ny + ukbl) : (8 + 2 * ny + (ukbl - 2));
    const size_t dst = ((size_t)((rg20 + uq) * 16 + KB) * 2 + us) * 512 + w;
    *(short8*)(A2F + dst) = *(const short8*)(outb + lin);
  }
}

// ---------------------------------------------------------------------------
// gemm2_lds: mirror of gemm1's LDS-A structure, no halo. Depth-3 (4 bufs,
// 32KB). Wave = 16-col W strip x 64 rows (4 row-frags, 12 MFMA/step).
// Cohort/step = 2 stage + 2 W = 4; steady vmcnt(8); tails 4 -> 0.
// ---------------------------------------------------------------------------
#define STAGE2(jn, kb) do {                                                  \
  gl_lds16(srcv0 + (kb) * 1024, sb2 + (jn) * 4096 + v0 * 512);               \
  gl_lds16(srcv1 + (kb) * 1024, sb2 + (jn) * 4096 + v1 * 512);               \
} while (0)

#define COMPK(j, WH, WL) do {                                                \
  const ushort* bp_ = sb2 + (j) * 4096 + lane * 8;                           \
  const short8 a0h = *(const short8*)(bp_ + 0 * 512);                        \
  const short8 a0l = *(const short8*)(bp_ + 1 * 512);                        \
  const short8 a1h = *(const short8*)(bp_ + 2 * 512);                        \
  const short8 a1l = *(const short8*)(bp_ + 3 * 512);                        \
  const short8 a2h = *(const short8*)(bp_ + 4 * 512);                        \
  const short8 a2l = *(const short8*)(bp_ + 5 * 512);                        \
  const short8 a3h = *(const short8*)(bp_ + 6 * 512);                        \
  const short8 a3l = *(const short8*)(bp_ + 7 * 512);                        \
  __builtin_amdgcn_s_setprio(1);                                            \
  MF(a0h, WH, acc[0]); MF(a1h, WH, acc[1]);                                  \
  MF(a2h, WH, acc[2]); MF(a3h, WH, acc[3]);                                  \
  MF(a0h, WL, acc[0]); MF(a1h, WL, acc[1]);                                  \
  MF(a2h, WL, acc[2]); MF(a3h, WL, acc[3]);                                  \
  MF(a0l, WH, acc[0]); MF(a1l, WH, acc[1]);                                  \
  MF(a2l, WH, acc[2]); MF(a3l, WH, acc[3]);                                  \
  __builtin_amdgcn_s_setprio(0);                                            \
  __builtin_amdgcn_sched_barrier(0);                                        \
} while (0)

__global__ __launch_bounds__(256, 2) void gemm2_lds(
    const ushort* __restrict__ A, const ushort* __restrict__ W,
    const float* __restrict__ bias, float* __restrict__ out) {
  __shared__ __align__(16) ushort sb2[4 * 4096];   // 32 KB

  const int tid = threadIdx.x;
  const int wave = tid >> 6, lane = tid & 63;
  const int lr = lane & 15, kg = lane >> 4;
  const int mx = blockIdx.x, ny = blockIdx.y;
  const int rg0 = mx * 4;                     // 4 A row-groups (64 rows)
  const int ngw = ny * 4 + wave;              // W col-group for this wave
  const int n0col = ngw * 16;

  const int v0 = wave * 2, v1 = wave * 2 + 1; // A staging units
  auto srcA = [&](int u) {
    return A + ((size_t)(rg0 + (u >> 1)) * 32 + (u & 1)) * 512 + lane * 8;
  };
  const ushort* srcv0 = srcA(v0);
  const ushort* srcv1 = srcA(v1);
  const ushort* bW = W + (size_t)ngw * 16384 + lane * 8;

  f32x4 acc[4] = {};
  short8 w0h, w0l, w1h, w1l, w2h, w2l, w3h, w3l;

  STAGE2(0, 0); GLOAD(w0h, bW);        GLOAD(w0l, bW + 512);
  STAGE2(1, 1); GLOAD(w1h, bW + 1024); GLOAD(w1l, bW + 1536);
  STAGE2(2, 2); GLOAD(w2h, bW + 2048); GLOAD(w2l, bW + 2560);

#define STEP2(k, j, jn, WH, WL, NWH, NWL)                                    \
  WAITV(8); __builtin_amdgcn_s_barrier();                                    \
  COMPK(j, WH, WL);                                                          \
  STAGE2(jn, (k) + 3);                                                       \
  GLOAD(NWH, bW + ((k) + 3) * 1024); GLOAD(NWL, bW + ((k) + 3) * 1024 + 512)

  STEP2(0,  0, 3, w0h, w0l, w3h, w3l);
  STEP2(1,  1, 0, w1h, w1l, w0h, w0l);
  STEP2(2,  2, 1, w2h, w2l, w1h, w1l);
  STEP2(3,  3, 2, w3h, w3l, w2h, w2l);
  STEP2(4,  0, 3, w0h, w0l, w3h, w3l);
  STEP2(5,  1, 0, w1h, w1l, w0h, w0l);
  STEP2(6,  2, 1, w2h, w2l, w1h, w1l);
  STEP2(7,  3, 2, w3h, w3l, w2h, w2l);
  STEP2(8,  0, 3, w0h, w0l, w3h, w3l);
  STEP2(9,  1, 0, w1h, w1l, w0h, w0l);
  STEP2(10, 2, 1, w2h, w2l, w1h, w1l);
  STEP2(11, 3, 2, w3h, w3l, w2h, w2l);
  STEP2(12, 0, 3, w0h, w0l, w3h, w3l);
  WAITV(8); __builtin_amdgcn_s_barrier(); COMPK(1, w1h, w1l);
  WAITV(4); __builtin_amdgcn_s_barrier(); COMPK(2, w2h, w2l);
  WAITV(0); __builtin_amdgcn_s_barrier(); COMPK(3, w3h, w3l);
#undef STEP2

  // epilogue: bias + fast tanh, row-major f32 out (compiler vmem after drain)
  const float bv = bias[n0col + lr];
  #pragma unroll
  for (int fr = 0; fr < 4; ++fr)
    #pragma unroll
    for (int r = 0; r < 4; ++r) {
      const int row = mx * 64 + fr * 16 + kg * 4 + r;
      out[(size_t)row * FEATC + n0col + lr] = tanh_fast(acc[fr][r] + bv);
    }
}

}  // namespace

extern "C" void kernel_launch(void* const* d_in, const int* in_sizes, int n_in,
                              void* d_out, int out_size, void* d_ws, size_t ws_size,
                              hipStream_t stream) {
  const float* x     = (const float*)d_in[0];
  const float* nodes = (const float*)d_in[1];
  // d_in[2] = edge_weight: forward value ew/ew == 1.0 -> unused.
  const float* W1s = (const float*)d_in[3];
  const float* W1n = (const float*)d_in[4];
  const float* b1  = (const float*)d_in[5];
  const float* W2s = (const float*)d_in[6];
  const float* W2n = (const float*)d_in[7];
  const float* b2  = (const float*)d_in[8];
  float* out = (float*)d_out;

  // workspace (ushort): A1F + A2F + WF1 + WF2 = 36.7 MB
  const size_t a1_sz = (size_t)BQ * M1 * 1024;      // 9,437,184
  const size_t a2_sz = (size_t)BQ * M2 * 1024;      // 8,388,608
  const size_t wf_sz = (size_t)16 * 16 * 2 * 512;   // 262,144 per layer
  const size_t need = (a1_sz + a2_sz + 2 * wf_sz) * sizeof(ushort);
  if (ws_size < need) return;

  ushort* p = (ushort*)d_ws;
  ushort* A1F = p; p += a1_sz;
  ushort* A2F = p; p += a2_sz;
  ushort* WF1 = p; p += wf_sz;
  ushort* WF2 = p; p += wf_sz;

  prep_fused<<<640, 256, 0, stream>>>(x, nodes, W1s, W1n, W2s, W2n,
                                      A1F, WF1, WF2);
  gemm1_fused<<<dim3(BQ * 2, FEATC / 64), 256, 0, stream>>>(A1F, WF1, b1, A2F);
  gemm2_lds<<<dim3((BQ * M2) / 64, FEATC / 64), 256, 0, stream>>>(
      A2F, WF2, b2, out);
}